// Round 2
// baseline (240.289 us; speedup 1.0000x reference)
//
#include <hip/hip_runtime.h>

#define BB 2048
#define TT 2048
#define CC 8
#define AA 27
#define HH 8

// One thread per output element (idx = b*T + t). Block = 256 threads covers
// 256 consecutive t within ONE sample b (T=2048 is a multiple of 256), so the
// per-sample MLP is recomputed cooperatively by 8 threads per block into LDS.
// All tensors are float32 (reference dtypes).
__global__ __launch_bounds__(256) void regional_conv2(
    const float* __restrict__ x,          // [B,T,C]
    const float* __restrict__ attrs,      // [B,A]
    const float* __restrict__ w1,         // [A,H]
    const float* __restrict__ b1,         // [H]
    const float* __restrict__ w2,         // [H,C]
    const float* __restrict__ b2,         // [C]
    const float* __restrict__ bw1,        // [A,H]
    const float* __restrict__ bb1,        // [H]
    const float* __restrict__ bw2,        // [H,1]
    const float* __restrict__ bb2,        // [1]
    const float* __restrict__ mask_attrs, // [B,A]
    const float* __restrict__ mask_hidden,// [B,H]
    float* __restrict__ out)              // [B,T,1]
{
    const int idx = blockIdx.x * 256 + threadIdx.x;   // b*T + t
    const int b   = idx >> 11;                        // T = 2048

    // Issue the streaming loads FIRST (2 × 16 B = 8 f32 channels); overlap
    // the latency with the tiny MLP below.
    const float4* xp = reinterpret_cast<const float4*>(x + (size_t)idx * CC);
    const float4 x0 = xp[0];
    const float4 x1 = xp[1];

    __shared__ float s_h[2 * HH];   // [0:H) = hw, [H:2H) = hb
    __shared__ float s_ker[CC];
    __shared__ float s_bias;

    const int tid = threadIdx.x;

    if (tid < HH) {
        // hidden unit `tid` of both branches; a[] computed on the fly
        float hw = b1[tid];
        float hb = bb1[tid];
        const float* ab = attrs      + b * AA;
        const float* mb = mask_attrs + b * AA;
        #pragma unroll
        for (int i = 0; i < AA; ++i) {
            const float a = ab[i] * mb[i];
            hw = fmaf(a, w1 [i * HH + tid], hw);
            hb = fmaf(a, bw1[i * HH + tid], hb);
        }
        const float mh = mask_hidden[b * HH + tid];
        s_h[tid]      = fmaxf(hw, 0.0f) * mh;
        s_h[HH + tid] = fmaxf(hb, 0.0f) * mh;
    }
    __syncthreads();

    if (tid < CC) {
        float acc = b2[tid];
        #pragma unroll
        for (int j = 0; j < HH; ++j)
            acc = fmaf(s_h[j], w2[j * CC + tid], acc);
        s_ker[tid] = tanhf(acc);
        if (tid == 0) {
            float accb = bb2[0];
            #pragma unroll
            for (int j = 0; j < HH; ++j)
                accb = fmaf(s_h[HH + j], bw2[j], accb);
            s_bias = tanhf(accb);
        }
    }
    __syncthreads();

    // dot(x[b,t,:], ker[b,:]) + bias, then ELU (alpha = 1)
    float y = s_bias;
    y = fmaf(x0.x, s_ker[0], y);
    y = fmaf(x0.y, s_ker[1], y);
    y = fmaf(x0.z, s_ker[2], y);
    y = fmaf(x0.w, s_ker[3], y);
    y = fmaf(x1.x, s_ker[4], y);
    y = fmaf(x1.y, s_ker[5], y);
    y = fmaf(x1.z, s_ker[6], y);
    y = fmaf(x1.w, s_ker[7], y);
    out[idx] = (y > 0.0f) ? y : expm1f(y);
}

extern "C" void kernel_launch(void* const* d_in, const int* in_sizes, int n_in,
                              void* d_out, int out_size, void* d_ws, size_t ws_size,
                              hipStream_t stream) {
    const float* x    = (const float*)d_in[0];
    const float* at   = (const float*)d_in[1];
    const float* w1   = (const float*)d_in[2];
    const float* b1   = (const float*)d_in[3];
    const float* w2   = (const float*)d_in[4];
    const float* b2   = (const float*)d_in[5];
    const float* bw1  = (const float*)d_in[6];
    const float* bb1  = (const float*)d_in[7];
    const float* bw2  = (const float*)d_in[8];
    const float* bb2  = (const float*)d_in[9];
    const float* ma   = (const float*)d_in[10];
    const float* mh   = (const float*)d_in[11];
    float* out = (float*)d_out;

    const int total  = BB * TT;           // 4,194,304 output elements
    const int blocks = total / 256;       // 16,384 blocks, b uniform per block
    regional_conv2<<<blocks, 256, 0, stream>>>(
        x, at, w1, b1, w2, b2, bw1, bb1, bw2, bb2, ma, mh, out);
}

// Round 3
// 215.213 us; speedup vs baseline: 1.1165x; 1.1165x over previous
//
#include <hip/hip_runtime.h>

#define BB 2048
#define TT 2048
#define CC 8
#define AA 27
#define HH 8

// ---------------- Kernel 1: per-sample MLP -> ws ----------------
// 2048 samples; block = 256 threads = 32 samples x 8 hidden-units.
// Latency of the 27-step attr loop is hidden by 16K concurrent threads
// spread over all CUs instead of serializing inside every streaming block.
__global__ __launch_bounds__(256) void mlp_kernel(
    const float* __restrict__ attrs,      // [B,A]
    const float* __restrict__ w1,         // [A,H]
    const float* __restrict__ b1,         // [H]
    const float* __restrict__ w2,         // [H,C]
    const float* __restrict__ b2,         // [C]
    const float* __restrict__ bw1,        // [A,H]
    const float* __restrict__ bb1,        // [H]
    const float* __restrict__ bw2,        // [H,1]
    const float* __restrict__ bb2,        // [1]
    const float* __restrict__ mask_attrs, // [B,A]
    const float* __restrict__ mask_hidden,// [B,H]
    float* __restrict__ ker,              // [B,C]  (ws)
    float* __restrict__ bias)             // [B]    (ws)
{
    const int tid = threadIdx.x;
    const int s   = tid >> 3;             // local sample 0..31
    const int h   = tid & 7;              // hidden unit / out channel
    const int b   = blockIdx.x * 32 + s;

    __shared__ float s_hw[32][HH];
    __shared__ float s_hb[32][HH];

    {
        float hw = b1[h];
        float hb = bb1[h];
        const float* ab = attrs      + b * AA;
        const float* mb = mask_attrs + b * AA;
        #pragma unroll
        for (int i = 0; i < AA; ++i) {
            const float a = ab[i] * mb[i];
            hw = fmaf(a, w1 [i * HH + h], hw);
            hb = fmaf(a, bw1[i * HH + h], hb);
        }
        const float mh = mask_hidden[b * HH + h];
        s_hw[s][h] = fmaxf(hw, 0.0f) * mh;
        s_hb[s][h] = fmaxf(hb, 0.0f) * mh;
    }
    __syncthreads();

    {
        const int c = h;
        float acc = b2[c];
        #pragma unroll
        for (int j = 0; j < HH; ++j)
            acc = fmaf(s_hw[s][j], w2[j * CC + c], acc);
        ker[b * CC + c] = tanhf(acc);
        if (c == 0) {
            float accb = bb2[0];
            #pragma unroll
            for (int j = 0; j < HH; ++j)
                accb = fmaf(s_hb[s][j], bw2[j], accb);
            bias[b] = tanhf(accb);
        }
    }
}

// ---------------- Kernel 2: pure streaming contraction ----------------
// One thread per output element, NO barriers, no redundant MLP.
// ker/bias rows are L1/L2-hot (73 KB total, read 16384x).
__global__ __launch_bounds__(256) void stream_kernel(
    const float* __restrict__ x,          // [B,T,C]
    const float* __restrict__ ker,        // [B,C]
    const float* __restrict__ bias,       // [B]
    float* __restrict__ out)              // [B,T]
{
    const int idx = blockIdx.x * 256 + threadIdx.x;   // b*T + t
    const int b   = idx >> 11;                        // T = 2048

    // streaming loads first (32 B/lane, coalesced 2 KB/wave)
    const float4* xp = reinterpret_cast<const float4*>(x + (size_t)idx * CC);
    const float4 x0 = xp[0];
    const float4 x1 = xp[1];

    // hot broadcast loads (same address across the whole block)
    const float4* kp = reinterpret_cast<const float4*>(ker + b * CC);
    const float4 k0 = kp[0];
    const float4 k1 = kp[1];
    float y = bias[b];

    y = fmaf(x0.x, k0.x, y);
    y = fmaf(x0.y, k0.y, y);
    y = fmaf(x0.z, k0.z, y);
    y = fmaf(x0.w, k0.w, y);
    y = fmaf(x1.x, k1.x, y);
    y = fmaf(x1.y, k1.y, y);
    y = fmaf(x1.z, k1.z, y);
    y = fmaf(x1.w, k1.w, y);
    out[idx] = (y > 0.0f) ? y : expm1f(y);   // ELU, alpha=1
}

extern "C" void kernel_launch(void* const* d_in, const int* in_sizes, int n_in,
                              void* d_out, int out_size, void* d_ws, size_t ws_size,
                              hipStream_t stream) {
    const float* x    = (const float*)d_in[0];
    const float* at   = (const float*)d_in[1];
    const float* w1   = (const float*)d_in[2];
    const float* b1   = (const float*)d_in[3];
    const float* w2   = (const float*)d_in[4];
    const float* b2   = (const float*)d_in[5];
    const float* bw1  = (const float*)d_in[6];
    const float* bb1  = (const float*)d_in[7];
    const float* bw2  = (const float*)d_in[8];
    const float* bb2  = (const float*)d_in[9];
    const float* ma   = (const float*)d_in[10];
    const float* mh   = (const float*)d_in[11];
    float* out = (float*)d_out;

    float* ker  = (float*)d_ws;                  // [B*C]  64 KB
    float* bias = (float*)d_ws + BB * CC;        // [B]     8 KB

    mlp_kernel<<<BB / 32, 256, 0, stream>>>(
        at, w1, b1, w2, b2, bw1, bb1, bw2, bb2, ma, mh, ker, bias);

    const int total  = BB * TT;                  // 4,194,304 elements
    stream_kernel<<<total / 256, 256, 0, stream>>>(x, ker, bias, out);
}